// Round 7
// baseline (53.608 us; speedup 1.0000x reference)
//
#include <hip/hip_runtime.h>
#include <hip/hip_bf16.h>
#include <stdint.h>

// Quanvolution + linear(784->10) + log_softmax via MFMA, B=65536, fp32 in/out.
// R6: R5's validated MFMA structure + K-split across a wave pair for 2x TLP.
//  - 4096 blocks x 128 thr (2 waves). Block owns 16 rows.
//  - wave kh handles K-blocks [14kh, 14kh+14); accumulators merged via 1KB LDS.
//  - 32 waves/CU (8/SIMD) vs R5's 16 -> latency hiding doubles.
//  - launch_bounds(128,8) caps VGPR at 64; unroll 2 + pointer-advance
//    (imm-offset loads) keeps pressure under the cap.
// K-permutation (same as R5): kp = 32*kb + 8*kg + e, kb = 2*pr + h,
// pc = h*7 + 2*kg + (e>>2); W baked permuted/padded bf16 [16][896] in d_ws.

typedef __attribute__((ext_vector_type(8))) short short8;
typedef __attribute__((ext_vector_type(4))) float f32x4;

// ---- pre-kernel: bake W -> bf16 [16][896], permuted + zero-padded ----
__global__ void quanv_wprep_kernel(const float* __restrict__ Wm,
                                   uint32_t* __restrict__ ws) {
    const int idx = blockIdx.x * 256 + threadIdx.x;   // [0, 7168)
    if (idx >= 16 * 448) return;
    const int n  = idx / 448;
    const int kk = idx - n * 448;     // u32 slot; holds kp=2kk, 2kk+1
    uint32_t outv = 0;
    if (n < 10) {
        const int kp = 2 * kk;
        const int kb = kp >> 5, r5 = kp & 31, kg = r5 >> 3, e0 = r5 & 7;
        const int pr = kb >> 1, h = kb & 1;
        uint32_t halves[2];
#pragma unroll
        for (int d = 0; d < 2; ++d) {
            const int e = e0 + d;                  // same kb,kg for both
            const int pc = h * 7 + 2 * kg + (e >> 2);
            float v = 0.f;
            if (kg < 3 || e < 4) v = Wm[n * 784 + (pr * 14 + pc) * 4 + (e & 3)];
            halves[d] = (uint32_t)__bfloat16_as_ushort(__float2bfloat16(v));
        }
        outv = halves[0] | (halves[1] << 16);
    }
    ws[idx] = outv;
}

// ---- main kernel ----
__global__ __launch_bounds__(128, 8)
void quanv_mfma2_kernel(const float* __restrict__ x,
                        const char* __restrict__ wsb,   // bf16 W [16][896]
                        const float* __restrict__ bias,
                        float* __restrict__ out) {
    __shared__ f32x4 red[64];   // 1 KB: kh=1 wave's accumulator tile

    const int t    = threadIdx.x;
    const int l    = t & 63;
    const int kh   = __builtin_amdgcn_readfirstlane(t >> 6);  // K-half 0/1
    const int r16  = l & 15;       // A-row (x row) and B-col (class)
    const int kg   = l >> 4;       // k-group 0..3
    const int rowBase = blockIdx.x * 16;
    // kh=1 starts at kb=14 -> pr offset 7 -> +392 floats
    const float* xr = x + (size_t)(rowBase + r16) * 784 + 392 * kh;

    const float* xT  = xr + 4 * kg;                        // top float4
    const float* xBa = xT + 28;                            // patchA bottom
    const float* xBb = (kg < 3) ? (xT + 30) : xr;          // patchB bottom/pad
    const char*  wb  = wsb + 1792 * r16 + 16 * kg + 896 * kh;

    f32x4 acc = {0.f, 0.f, 0.f, 0.f};

#pragma unroll 2
    for (int j = 0; j < 7; ++j) {
        // two K-blocks per j: h=0 at +0 floats, h=1 at +14 floats
#pragma unroll
        for (int h = 0; h < 2; ++h) {
            const int off = 14 * h;                        // imm offsets
            const float4 T  = *(const float4*)(xT  + off);
            const float2 bA = *(const float2*)(xBa + off);
            const float2 bB = *(const float2*)(xBb + off);

            float f[8];
            {   // patch A: pc = h*7 + 2*kg (always real)
                const float p0 = T.x, p1 = T.y, p2 = bA.x, p3 = bA.y;
                const float c0 = __cosf(p0), c1 = __cosf(p1);
                const float c2 = __cosf(p2), c3 = __cosf(p3);
                f[0] = c0 + p0; f[1] = c0 * c1 + p1;
                f[2] = c2 + p2; f[3] = c2 * c3 + p3;
            }
            {   // patch B: pc+1 (pad for kg==3 -> W=0 annihilates)
                const float p0 = T.z, p1 = T.w, p2 = bB.x, p3 = bB.y;
                const float c0 = __cosf(p0), c1 = __cosf(p1);
                const float c2 = __cosf(p2), c3 = __cosf(p3);
                f[4] = c0 + p0; f[5] = c0 * c1 + p1;
                f[6] = c2 + p2; f[7] = c2 * c3 + p3;
            }

            short8 a;
#pragma unroll
            for (int e = 0; e < 8; ++e)
                a[e] = (short)__bfloat16_as_ushort(__float2bfloat16(f[e]));

            const short8 b = *(const short8*)(wb + 64 * h);
            acc = __builtin_amdgcn_mfma_f32_16x16x32_bf16(a, b, acc, 0, 0, 0);
        }
        xT += 56; xBa += 56; xBb += 56; wb += 128;
    }

    // ---- merge K-halves via LDS ----
    if (kh == 1) red[l] = acc;
    __syncthreads();
    if (kh == 0) {
        const f32x4 o = red[l];
#pragma unroll
        for (int j = 0; j < 4; ++j) acc[j] += o[j];

        // ---- epilogue: lane holds D[m=4*kg+j][n=r16]; log_softmax over n ----
        const float bn = bias[r16 < 10 ? r16 : 0];
#pragma unroll
        for (int j = 0; j < 4; ++j) {
            float v = (r16 < 10) ? (acc[j] + bn) : -1e30f;
            float mx = v;
            mx = fmaxf(mx, __shfl_xor(mx, 1, 64));
            mx = fmaxf(mx, __shfl_xor(mx, 2, 64));
            mx = fmaxf(mx, __shfl_xor(mx, 4, 64));
            mx = fmaxf(mx, __shfl_xor(mx, 8, 64));
            float e = (r16 < 10) ? __expf(v - mx) : 0.f;
            float s = e;
            s += __shfl_xor(s, 1, 64);
            s += __shfl_xor(s, 2, 64);
            s += __shfl_xor(s, 4, 64);
            s += __shfl_xor(s, 8, 64);
            const float ls = __logf(s) + mx;
            if (r16 < 10)
                out[(size_t)(rowBase + 4 * kg + j) * 10 + r16] = v - ls;
        }
    }
}

extern "C" void kernel_launch(void* const* d_in, const int* in_sizes, int n_in,
                              void* d_out, int out_size, void* d_ws, size_t ws_size,
                              hipStream_t stream) {
    const float* x    = (const float*)d_in[0];   // [65536, 784]
    const float* Wm   = (const float*)d_in[1];   // [10, 784]
    const float* bias = (const float*)d_in[2];   // [10]
    float* out        = (float*)d_out;           // [65536, 10]

    quanv_wprep_kernel<<<dim3(28), dim3(256), 0, stream>>>(
        Wm, (uint32_t*)d_ws);
    quanv_mfma2_kernel<<<dim3(4096), dim3(128), 0, stream>>>(
        x, (const char*)d_ws, bias, out);
}

// Round 8
// 45.916 us; speedup vs baseline: 1.1675x; 1.1675x over previous
//
#include <hip/hip_runtime.h>
#include <hip/hip_bf16.h>
#include <stdint.h>

// Quanvolution + linear(784->10) + log_softmax via MFMA, B=65536, fp32 in/out.
// R7: VMEM floor. New K-permutation: within K-block (pr,half), lane (r16,kg)
// owns 8 CONTIGUOUS floats of the patch-row -> exactly 2 aligned float4
// loads per K-block (the fp32 floor). W-fragments preloaded to VGPRs
// (14 x short8 = 56 VGPR), baked dense [kb][lane][e] by the pre-kernel.
// No W loads, no branches, no LDS in the main loop; 1 barrier total.
//
// K-slot map (kb = 2*pr + half), s = pr*56:
//  half0: kg0: tops of patches 0..3  = floats s+0..7    (f0/f1 pairs)
//         kg1: tops of patches 4..7  = floats s+8..15
//         kg2: bottoms patches 0..3  = floats s+28..35  (f2/f3 pairs)
//         kg3: bottoms patches 4..7  = floats s+36..43
//  half1: kg0: tops patches 8..11    = floats s+16..23
//         kg1: [4 pad] + tops 12,13  = floats s+20..27 (e<4 -> W=0)
//         kg2: bottoms patches 8..11 = floats s+44..51
//         kg3: [4 pad] + bottoms 12,13 = floats s+48..55 (e<4 -> W=0)
// Feature per pair (pe,po): g_even = cos(pe)+pe ; g_odd = cos(pe)*cos(po)+po
// -> identical formula for top (f0,f1) and bottom (f2,f3) slots.

typedef __attribute__((ext_vector_type(8))) short short8;
typedef __attribute__((ext_vector_type(4))) float f32x4;

// ---- pre-kernel: bake W -> bf16 frags ws[kb][lane][e], 28 KB ----
__global__ void quanv_wprep_kernel(const float* __restrict__ Wm,
                                   uint32_t* __restrict__ ws) {
    const int idx = blockIdx.x * 256 + threadIdx.x;   // [0, 7168)
    if (idx >= 7168) return;
    const int kb   = idx >> 8;      // 0..27
    const int rem  = idx & 255;
    const int l    = rem >> 2;      // lane 0..63
    const int d    = rem & 3;       // u32 pair -> e = 2d, 2d+1
    const int n    = l & 15;
    const int kg   = l >> 4;
    const int pr   = kb >> 1;
    const int half = kb & 1;
    uint32_t outv = 0;
    if (n < 10) {
        uint32_t hv[2];
#pragma unroll
        for (int d2 = 0; d2 < 2; ++d2) {
            const int e  = 2 * d + d2;
            const int fi = ((kg >= 2) ? 2 : 0) + (e & 1);
            int j; bool pad = false;
            if (half == 0) {
                j = 4 * (kg & 1) + (e >> 1);
            } else if ((kg & 1) == 0) {
                j = 8 + (e >> 1);
            } else {
                pad = (e < 4);
                const int e4 = (e >= 4) ? (e - 4) : 0;
                j = 12 + (e4 >> 1);
            }
            const float v = pad ? 0.f : Wm[n * 784 + (pr * 14 + j) * 4 + fi];
            hv[d2] = (uint32_t)__bfloat16_as_ushort(__float2bfloat16(v));
        }
        outv = hv[0] | (hv[1] << 16);
    }
    ws[idx] = outv;
}

// ---- one K-block: 2 adjacent float4 loads -> 8 features -> 1 MFMA ----
#define QKB(P, IMM, WF) do {                                                  \
    const float4 va = *(const float4*)((P) + (IMM));                          \
    const float4 vb = *(const float4*)((P) + (IMM) + 4);                      \
    float g0,g1,g2,g3,g4,g5,g6,g7;                                            \
    { const float ce=__cosf(va.x), co=__cosf(va.y);                           \
      g0 = ce + va.x; g1 = fmaf(ce, co, va.y); }                              \
    { const float ce=__cosf(va.z), co=__cosf(va.w);                           \
      g2 = ce + va.z; g3 = fmaf(ce, co, va.w); }                              \
    { const float ce=__cosf(vb.x), co=__cosf(vb.y);                           \
      g4 = ce + vb.x; g5 = fmaf(ce, co, vb.y); }                              \
    { const float ce=__cosf(vb.z), co=__cosf(vb.w);                           \
      g6 = ce + vb.z; g7 = fmaf(ce, co, vb.w); }                              \
    short8 a;                                                                 \
    a[0]=(short)__bfloat16_as_ushort(__float2bfloat16(g0));                   \
    a[1]=(short)__bfloat16_as_ushort(__float2bfloat16(g1));                   \
    a[2]=(short)__bfloat16_as_ushort(__float2bfloat16(g2));                   \
    a[3]=(short)__bfloat16_as_ushort(__float2bfloat16(g3));                   \
    a[4]=(short)__bfloat16_as_ushort(__float2bfloat16(g4));                   \
    a[5]=(short)__bfloat16_as_ushort(__float2bfloat16(g5));                   \
    a[6]=(short)__bfloat16_as_ushort(__float2bfloat16(g6));                   \
    a[7]=(short)__bfloat16_as_ushort(__float2bfloat16(g7));                   \
    acc = __builtin_amdgcn_mfma_f32_16x16x32_bf16(a, (WF), acc, 0, 0, 0);     \
} while (0)

__global__ __launch_bounds__(256, 4)
void quanv_mfma3_kernel(const float* __restrict__ x,
                        const char* __restrict__ wsb,   // bf16 frags [28][64][8]
                        const float* __restrict__ bias,
                        float* __restrict__ out) {
    __shared__ f32x4 red[2][64];   // 2 KB: kh=1 accumulators

    const int t   = threadIdx.x;
    const int l   = t & 63;
    const int w   = t >> 6;
    const int rg  = __builtin_amdgcn_readfirstlane(w >> 1);   // row-group 0/1
    const int kh  = __builtin_amdgcn_readfirstlane(w & 1);    // K-half 0/1
    const int r16 = l & 15;        // A-row (x row) / B-col (class)
    const int kg  = l >> 4;        // k-group 0..3
    const int rowBase = blockIdx.x * 32 + rg * 16;
    const float* xr = x + (size_t)(rowBase + r16) * 784 + kh * 392;

    // per-lane contiguous 8-float base offsets (see map above)
    const int off0 = (kg == 0) ? 0  : (kg == 1) ? 8  : (kg == 2) ? 28 : 36;
    const int off1 = (kg == 0) ? 16 : (kg == 1) ? 20 : (kg == 2) ? 44 : 48;
    const float* p0 = xr + off0;   // half-0 K-blocks
    const float* p1 = xr + off1;   // half-1 K-blocks

    // preload my 14 W-fragments (56 VGPR), coalesced 1KB per kb
    const char* wbp = wsb + kh * 14336 + l * 16;
    const short8 wf0  = *(const short8*)(wbp + 0  * 1024);
    const short8 wf1  = *(const short8*)(wbp + 1  * 1024);
    const short8 wf2  = *(const short8*)(wbp + 2  * 1024);
    const short8 wf3  = *(const short8*)(wbp + 3  * 1024);
    const short8 wf4  = *(const short8*)(wbp + 4  * 1024);
    const short8 wf5  = *(const short8*)(wbp + 5  * 1024);
    const short8 wf6  = *(const short8*)(wbp + 6  * 1024);
    const short8 wf7  = *(const short8*)(wbp + 7  * 1024);
    const short8 wf8  = *(const short8*)(wbp + 8  * 1024);
    const short8 wf9  = *(const short8*)(wbp + 9  * 1024);
    const short8 wf10 = *(const short8*)(wbp + 10 * 1024);
    const short8 wf11 = *(const short8*)(wbp + 11 * 1024);
    const short8 wf12 = *(const short8*)(wbp + 12 * 1024);
    const short8 wf13 = *(const short8*)(wbp + 13 * 1024);

    f32x4 acc = {0.f, 0.f, 0.f, 0.f};

    // 7 patch-rows x 2 halves, fully unrolled, imm offsets (max 1488B)
    QKB(p0, 0 * 56, wf0);  QKB(p1, 0 * 56, wf1);
    QKB(p0, 1 * 56, wf2);  QKB(p1, 1 * 56, wf3);
    QKB(p0, 2 * 56, wf4);  QKB(p1, 2 * 56, wf5);
    QKB(p0, 3 * 56, wf6);  QKB(p1, 3 * 56, wf7);
    QKB(p0, 4 * 56, wf8);  QKB(p1, 4 * 56, wf9);
    QKB(p0, 5 * 56, wf10); QKB(p1, 5 * 56, wf11);
    QKB(p0, 6 * 56, wf12); QKB(p1, 6 * 56, wf13);

    // ---- merge K-halves via LDS ----
    if (kh == 1) red[rg][l] = acc;
    __syncthreads();
    if (kh == 0) {
        const f32x4 o = red[rg][l];
#pragma unroll
        for (int j = 0; j < 4; ++j) acc[j] += o[j];

        // ---- epilogue: lane holds D[m=4*kg+j][n=r16]; log_softmax over n ----
        const float bn = bias[r16 < 10 ? r16 : 0];
#pragma unroll
        for (int j = 0; j < 4; ++j) {
            float v = (r16 < 10) ? (acc[j] + bn) : -1e30f;
            float mx = v;
            mx = fmaxf(mx, __shfl_xor(mx, 1, 64));
            mx = fmaxf(mx, __shfl_xor(mx, 2, 64));
            mx = fmaxf(mx, __shfl_xor(mx, 4, 64));
            mx = fmaxf(mx, __shfl_xor(mx, 8, 64));
            float e = (r16 < 10) ? __expf(v - mx) : 0.f;
            float s = e;
            s += __shfl_xor(s, 1, 64);
            s += __shfl_xor(s, 2, 64);
            s += __shfl_xor(s, 4, 64);
            s += __shfl_xor(s, 8, 64);
            const float ls = __logf(s) + mx;
            if (r16 < 10)
                out[(size_t)(rowBase + 4 * kg + j) * 10 + r16] = v - ls;
        }
    }
}

extern "C" void kernel_launch(void* const* d_in, const int* in_sizes, int n_in,
                              void* d_out, int out_size, void* d_ws, size_t ws_size,
                              hipStream_t stream) {
    const float* x    = (const float*)d_in[0];   // [65536, 784]
    const float* Wm   = (const float*)d_in[1];   // [10, 784]
    const float* bias = (const float*)d_in[2];   // [10]
    float* out        = (float*)d_out;           // [65536, 10]

    quanv_wprep_kernel<<<dim3(28), dim3(256), 0, stream>>>(
        Wm, (uint32_t*)d_ws);
    quanv_mfma3_kernel<<<dim3(2048), dim3(256), 0, stream>>>(
        x, (const char*)d_ws, bias, out);
}